// Round 9
// baseline (573.329 us; speedup 1.0000x reference)
//
#include <hip/hip_runtime.h>

typedef __attribute__((ext_vector_type(4))) float fv4;
typedef __attribute__((ext_vector_type(8))) _Float16 hv8;
typedef __attribute__((ext_vector_type(4))) _Float16 hv4;
typedef __attribute__((ext_vector_type(2))) _Float16 hv2;

// ---------------------------------------------------------------------------
// async global->LDS 16B copy (wave-uniform LDS base + lane*16 semantics)
// ---------------------------------------------------------------------------
__device__ __forceinline__ void gload16(const void* g, void* l) {
  __builtin_amdgcn_global_load_lds(
      (const __attribute__((address_space(1))) unsigned int*)g,
      (__attribute__((address_space(3))) unsigned int*)l, 16, 0, 0);
}

// ---------------------------------------------------------------------------
// 256x256 tile GEMM core, 8 waves (2M x 4N), per-wave 128x64 output.
// R4/R8 structure -- measured optimum across 6 schedule brackets
// (155 us @ L1, MfmaUtil ~40%). See R1-R7 journal: phase-split, 1-barrier,
// full-prefetch, 2-block TLP, fat-wave all matched or regressed.
// K in BK=32 steps through a 4-deep LDS ring (4 x 32 KiB = 128 KiB).
// Step: stage(s+3) -> vmcnt(8) -> s_barrier -> read b0(s), a47(s), a03(s+1)
// -> setprio(1) 32 MFMA setprio(0). vmcnt never 0 in main loop (tail 8->4->0).
// Swizzle (measured 0 conflicts): staged-side cg=(tid&3)^((tid>>3)&3) on the
// global source, fragment-side sq=quad^((r>>1)&3) on the ds_read.
// ---------------------------------------------------------------------------
struct GemmCore256 {
  const _Float16 *ap, *bp;   // per-thread pre-swizzled global sources
  size_t rstep;              // +128 rows in elements
  _Float16* ls;
  const _Float16 *fa, *fb;   // fragment read bases (ring slot 0)
  int wv;

  __device__ __forceinline__ void init(const _Float16* A, const _Float16* Bt,
                                       _Float16* lds, int m0, int n0, int K,
                                       int tid) {
    ls = lds;
    wv = tid >> 6;
    const int lane = tid & 63;
    const int wm = wv >> 2, wn = wv & 3;
    const int quad = lane >> 4, r = lane & 15;
    const int cg = (tid & 3) ^ ((tid >> 3) & 3);   // staged-side XOR swizzle
    ap = A  + (size_t)(m0 + (tid >> 2)) * K + cg * 8;
    bp = Bt + (size_t)(n0 + (tid >> 2)) * K + cg * 8;
    rstep = (size_t)128 * K;
    const int sq = quad ^ ((r >> 1) & 3);          // fragment-side swizzle
    fa = ls + (wm * 128 + r) * 32 + sq * 8;
    fb = ls + 8192 + (wn * 64 + r) * 32 + sq * 8;
  }

  __device__ __forceinline__ void stage4(int s) {   // full ring slot s&3
    _Float16* d = ls + (s & 3) * 16384 + wv * 512;
    const _Float16* a = ap + (size_t)s * 32;
    const _Float16* b = bp + (size_t)s * 32;
    gload16(a,         d);
    gload16(a + rstep, d + 4096);
    gload16(b,         d + 8192);
    gload16(b + rstep, d + 12288);
  }

  __device__ __forceinline__ void readA03(hv8 (&a)[4], int s) {
    const _Float16* fA = fa + (s & 3) * 16384;
#pragma unroll
    for (int t = 0; t < 4; ++t) a[t] = *(const hv8*)(fA + t * 512);
  }

  // one K-step; cur = prefetched a[0..3] of slot s; nxt filled for slot s+1
  template <int VM, bool STAGE>
  __device__ __forceinline__ void body(fv4 acc[8][4], hv8 (&nxt)[4],
                                       hv8 (&cur)[4], int s) {
    if (STAGE) stage4(s + 3);
    if constexpr (VM >= 0)
      asm volatile("s_waitcnt vmcnt(%0)" :: "n"(VM) : "memory");
    __builtin_amdgcn_s_barrier();
    asm volatile("" ::: "memory");   // pin LDS reads below the barrier
    const _Float16* fA = fa + (s & 3) * 16384;
    const _Float16* fB = fb + (s & 3) * 16384;
    hv8 b0[4], a47[4];
#pragma unroll
    for (int t = 0; t < 4; ++t) b0[t] = *(const hv8*)(fB + t * 512);
#pragma unroll
    for (int t = 0; t < 4; ++t) a47[t] = *(const hv8*)(fA + (t + 4) * 512);
    readA03(nxt, s + 1);             // prefetch: drains under the MFMAs
    __builtin_amdgcn_s_setprio(1);
#pragma unroll
    for (int tm = 0; tm < 4; ++tm)
#pragma unroll
      for (int tn = 0; tn < 4; ++tn)
        acc[tm][tn] = __builtin_amdgcn_mfma_f32_16x16x32_f16(cur[tm], b0[tn],
                                                             acc[tm][tn], 0, 0, 0);
#pragma unroll
    for (int tm = 0; tm < 4; ++tm)
#pragma unroll
      for (int tn = 0; tn < 4; ++tn)
        acc[tm + 4][tn] = __builtin_amdgcn_mfma_f32_16x16x32_f16(a47[tm], b0[tn],
                                                                 acc[tm + 4][tn], 0, 0, 0);
    __builtin_amdgcn_s_setprio(0);
  }

  __device__ __forceinline__ void bodyLast(fv4 acc[8][4], hv8 (&cur)[4], int s) {
    __builtin_amdgcn_s_barrier();
    asm volatile("" ::: "memory");
    const _Float16* fA = fa + (s & 3) * 16384;
    const _Float16* fB = fb + (s & 3) * 16384;
    hv8 b0[4], a47[4];
#pragma unroll
    for (int t = 0; t < 4; ++t) b0[t] = *(const hv8*)(fB + t * 512);
#pragma unroll
    for (int t = 0; t < 4; ++t) a47[t] = *(const hv8*)(fA + (t + 4) * 512);
    __builtin_amdgcn_s_setprio(1);
#pragma unroll
    for (int tm = 0; tm < 4; ++tm)
#pragma unroll
      for (int tn = 0; tn < 4; ++tn)
        acc[tm][tn] = __builtin_amdgcn_mfma_f32_16x16x32_f16(cur[tm], b0[tn],
                                                             acc[tm][tn], 0, 0, 0);
#pragma unroll
    for (int tm = 0; tm < 4; ++tm)
#pragma unroll
      for (int tn = 0; tn < 4; ++tn)
        acc[tm + 4][tn] = __builtin_amdgcn_mfma_f32_16x16x32_f16(a47[tm], b0[tn],
                                                                 acc[tm + 4][tn], 0, 0, 0);
    __builtin_amdgcn_s_setprio(0);
  }

  __device__ __forceinline__ void run(fv4 acc[8][4], int K) {
    const int ns = K >> 5;               // BK=32 steps (K = 512 or 1024, even)
    stage4(0); stage4(1); stage4(2);     // prime ring 3 deep (12 outstanding)
    asm volatile("s_waitcnt vmcnt(8)" ::: "memory");   // my slot-0 loads done
    __builtin_amdgcn_s_barrier();                       // collective
    asm volatile("" ::: "memory");
    hv8 p0[4], p1[4];                    // a[0..3] double-buffer (rule #20:
    readA03(p0, 0);                      //  static names, no runtime index)
    int s = 0;
    for (; s < ns - 4; s += 2) {
      body<8, true>(acc, p1, p0, s);
      body<8, true>(acc, p0, p1, s + 1);
    }
    body<8, true >(acc, p1, p0, ns - 4); // stages slot ns-1 (last)
    body<4, false>(acc, p0, p1, ns - 3); // tail guards: 8 -> 4 -> 0
    body<0, false>(acc, p1, p0, ns - 2);
    bodyLast(acc, p1, ns - 1);
  }
};

// XCD-colocation block swizzle (tile = 256): blocks sharing one A-strip get
// linear ids congruent mod 8 -> same XCD -> A-strip hits in its L2.
__device__ __forceinline__ void xcd_map(int bid, int ntl2, int mt_per_x,
                                        int& m0, int& n0) {
  const int xcd = bid & 7;
  const int k2  = bid >> 3;
  m0 = (xcd * mt_per_x + (k2 >> ntl2)) * 256;
  n0 = (k2 & ((1 << ntl2) - 1)) * 256;
}

// ---------------------------------------------------------------------------
// Fused layer GEMM + minGRU gate + scan phase A (256-tile, 8 waves).
// Btf[2048,K]: rows [b*64,b*64+32)=Wz cols, +32=Wh cols for j-block b.
// Per wave: 64-col slice -> tn 0,1 = zpre, tn 2,3 = hpre for j = jb+tn*16+r.
// Wave covers 128 rows = 2 scan chunks of 64 (tm 0-3 / tm 4-7); composition
// order identical to the verified version -> bit-identical cA/cB.
// ---------------------------------------------------------------------------
__global__ __launch_bounds__(512, 2)
void gemm_gate(const _Float16* __restrict__ A, const _Float16* __restrict__ Btf,
               _Float16* __restrict__ zh2,
               float* __restrict__ cA, float* __restrict__ cB,
               const float* __restrict__ bz, const float* __restrict__ bh,
               int K, int ntl2, int mt_per_x) {
  __shared__ _Float16 lds[4 * 16384];   // 128 KiB ring
  const int tid  = threadIdx.x;
  const int lane = tid & 63;
  const int wave = tid >> 6;
  const int wm = wave >> 2, wn = wave & 3;
  const int quad = lane >> 4, r = lane & 15;
  int m0, n0;
  xcd_map(blockIdx.x, ntl2, mt_per_x, m0, n0);

  GemmCore256 core;
  core.init(A, Btf, lds, m0, n0, K, tid);
  fv4 acc[8][4] = {};
  core.run(acc, K);

  // C/D layout: col = lane&15, row = quad*4 + reg (m89-verified).
  const int jb   = (n0 + wn * 64) >> 1;
  const int row0 = m0 + wm * 128 + quad * 4;
  const int cb   = (m0 >> 6) + wm * 2;   // first chunk index of this wave
#pragma unroll
  for (int tn = 0; tn < 2; ++tn) {
    const int j = jb + tn * 16 + r;
    const float bzv = bz[j];
    const float bhv = bh[j];
#pragma unroll
    for (int tg = 0; tg < 2; ++tg) {     // 64-row chunk within the wave
      float qA[4], qB[4];
#pragma unroll
      for (int tq = 0; tq < 4; ++tq) {
        const int tm = tg * 4 + tq;
        float sA = 1.0f, sB = 0.0f;
#pragma unroll
        for (int r2 = 0; r2 < 4; ++r2) {
          const float zpre = acc[tm][tn][r2] + bzv;
          const float hpre = acc[tm][tn + 2][r2] + bhv;
          const float z = 1.0f / (1.0f + __expf(-zpre));
          const _Float16 a16 = (_Float16)(1.0f - z);
          const _Float16 b16 = (_Float16)(z * hpre);
          hv2 ab = {a16, b16};
          *(hv2*)(zh2 + ((size_t)(row0 + tm * 16 + r2) * 1024 + j) * 2) = ab;
          const float af = (float)a16, bf = (float)b16;
          sB = af * sB + bf;   // ordered fold, r2 ascending
          sA = sA * af;
        }
        qA[tq] = sA; qB[tq] = sB;
      }
      // inclusive scan across quads (rows 16tq+4q+r2; quad ascending)
#pragma unroll
      for (int tq = 0; tq < 4; ++tq) {
        float Av = qA[tq], Bv = qB[tq];
        float Ap = __shfl_up(Av, 16, 64);
        float Bp = __shfl_up(Bv, 16, 64);
        if (quad >= 1) { Bv = Av * Bp + Bv; Av = Ap * Av; }
        Ap = __shfl_up(Av, 32, 64);
        Bp = __shfl_up(Bv, 32, 64);
        if (quad >= 2) { Bv = Av * Bp + Bv; Av = Ap * Av; }
        qA[tq] = Av; qB[tq] = Bv;
      }
      if (quad == 3) {   // lane holds full 16-row composition per tq
        float CA = 1.0f, CB = 0.0f;
#pragma unroll
        for (int tq = 0; tq < 4; ++tq) { CB = qA[tq] * CB + qB[tq]; CA *= qA[tq]; }
        cA[(size_t)(cb + tg) * 1024 + j] = CA;
        cB[(size_t)(cb + tg) * 1024 + j] = CB;
      }
    }
  }
}

// ---------------------------------------------------------------------------
// Plain GEMM (FC head): C[M,N] fp32 = A[M,K] f16 @ Bt[N,K]^T + bias
// ---------------------------------------------------------------------------
__global__ __launch_bounds__(512, 2)
void gemm_f16_bt(const _Float16* __restrict__ A, const _Float16* __restrict__ Bt,
                 float* __restrict__ C, const float* __restrict__ bias,
                 int N, int K, int ntl2, int mt_per_x) {
  __shared__ _Float16 lds[4 * 16384];
  const int tid  = threadIdx.x;
  const int lane = tid & 63;
  const int wave = tid >> 6;
  const int wm = wave >> 2, wn = wave & 3;
  const int quad = lane >> 4, r = lane & 15;
  int m0, n0;
  xcd_map(blockIdx.x, ntl2, mt_per_x, m0, n0);

  GemmCore256 core;
  core.init(A, Bt, lds, m0, n0, K, tid);
  fv4 acc[8][4] = {};
  core.run(acc, K);

  const int col0 = n0 + wn * 64 + r;
  const int row0 = m0 + wm * 128 + quad * 4;
#pragma unroll
  for (int tn = 0; tn < 4; ++tn) {
    const int col = col0 + tn * 16;
    const float bs = bias[col];
#pragma unroll
    for (int tm = 0; tm < 8; ++tm) {
#pragma unroll
      for (int r2 = 0; r2 < 4; ++r2) {
        C[(size_t)(row0 + tm * 16 + r2) * N + col] = acc[tm][tn][r2] + bs;
      }
    }
  }
}

// ---------------------------------------------------------------------------
// ONE preprocessing kernel: z=0..4 weight transposes (verified body), z>=5
// the x f32->f16 convert (verified body, re-gridded). Cuts 4 launches.
// ---------------------------------------------------------------------------
__global__ void prep_all(const float* __restrict__ x,
                         const float* __restrict__ Wz0,
                         const float* __restrict__ Wh0,
                         const float* __restrict__ Wz1,
                         const float* __restrict__ Wh1,
                         const float* __restrict__ Wfc,
                         _Float16* __restrict__ Xb,
                         _Float16* __restrict__ Wzh0t,
                         _Float16* __restrict__ Wzh1t,
                         _Float16* __restrict__ Wft) {
  const int z = blockIdx.z;
  if (z >= 5) {
    // cvt: slot covers 4096 floats; 4096 slots total = 16.78M = Mrows*Din
    const int slot = (z - 5) * 1024 + blockIdx.y * 32 + blockIdx.x;
    const int tid  = threadIdx.y * 32 + threadIdx.x;
    const size_t base = (size_t)slot * 4096 + tid * 4;
#pragma unroll
    for (int i = 0; i < 4; ++i) {
      fv4 v = *(const fv4*)(x + base + i * 1024);
      *(hv4*)(Xb + base + i * 1024) = __builtin_convertvector(v, hv4);
    }
    return;
  }
  const float* W; _Float16* Wt; int K, N, mult, off;
  if (z == 0)      { W = Wz0; Wt = Wzh0t; K = 512;  N = 1024; mult = 64; off = 0;  }
  else if (z == 1) { W = Wh0; Wt = Wzh0t; K = 512;  N = 1024; mult = 64; off = 32; }
  else if (z == 2) { W = Wz1; Wt = Wzh1t; K = 1024; N = 1024; mult = 64; off = 0;  }
  else if (z == 3) { W = Wh1; Wt = Wzh1t; K = 1024; N = 1024; mult = 64; off = 32; }
  else             { W = Wfc; Wt = Wft;   K = 1024; N = 512;  mult = 32; off = 0;  }
  if (blockIdx.x * 32 >= (unsigned)N || blockIdx.y * 32 >= (unsigned)K) return;

  __shared__ float tile[32][33];
  const int tx = threadIdx.x, ty = threadIdx.y;
  const int n  = blockIdx.x * 32 + tx;
  const int kb = blockIdx.y * 32;
  for (int i = ty; i < 32; i += 8)
    tile[i][tx] = W[(size_t)(kb + i) * N + n];
  __syncthreads();
  const int k = kb + tx;
  for (int i = ty; i < 32; i += 8)
    Wt[(size_t)(blockIdx.x * mult + off + i) * K + k] = (_Float16)tile[tx][i];
}

// ---------------------------------------------------------------------------
// FUSED scan (replaces phaseB + phaseC; one launch per layer instead of two).
// Block = (bb, chunk-pair c0..c0+1), 512 threads (8 waves). Part 1: each wave
// redoes the 64-chunk Hillis-Steele scan (lane = chunk) for 32 of the block's
// 256 h4-groups -- identical op order and inputs as the old scan_phaseB ->
// bit-identical hcy; the two lanes matching the block's chunks write their
// exclusive values to LDS (64x redundant block-level scans, but cA/cB is
// L2/L3-resident 4 MiB and the scans are a short ILP'd prologue).
// Part 2: identical to the old scan_phaseC (coalesced replay), hc seeded
// from LDS instead of the hcy buffer.
// ---------------------------------------------------------------------------
__global__ __launch_bounds__(512)
void scan_fused(const float* __restrict__ cA, const float* __restrict__ cB,
                const _Float16* __restrict__ zh2, _Float16* __restrict__ hout) {
  __shared__ float hcyL[2][256][4];
  const int tid  = threadIdx.x;
  const int lane = tid & 63;
  const int wv   = tid >> 6;
  const int bb   = blockIdx.x >> 5;
  const int c0   = (blockIdx.x & 31) * 2;

  // part 1: scan 32 h4-groups per wave (independent bodies -> ILP via unroll)
#pragma unroll 4
  for (int gi = 0; gi < 32; ++gi) {
    const int g = wv * 32 + gi;
    const size_t o = (size_t)(bb * 64 + lane) * 1024 + g * 4;
    fv4 Aa = *(const fv4*)(cA + o);
    fv4 Bv = *(const fv4*)(cB + o);
#pragma unroll
    for (int d = 1; d < 64; d <<= 1) {
      fv4 Ap, Bp;
#pragma unroll
      for (int k = 0; k < 4; ++k) {
        Ap[k] = __shfl_up(Aa[k], d, 64);
        Bp[k] = __shfl_up(Bv[k], d, 64);
      }
      if (lane >= d) {
        Bv = Aa * Bp + Bv;
        Aa = Ap * Aa;
      }
    }
    fv4 hc;
#pragma unroll
    for (int k = 0; k < 4; ++k) hc[k] = __shfl_up(Bv[k], 1, 64);
    if (lane == 0) { hc.x = 0.f; hc.y = 0.f; hc.z = 0.f; hc.w = 0.f; }
    if (lane == c0) {
#pragma unroll
      for (int k = 0; k < 4; ++k) hcyL[0][g][k] = hc[k];
    }
    if (lane == c0 + 1) {
#pragma unroll
      for (int k = 0; k < 4; ++k) hcyL[1][g][k] = hc[k];
    }
  }
  __syncthreads();

  // part 2: chunk replay (identical to old scan_phaseC)
  const int ci = tid >> 8;          // 0/1 -> which chunk of the pair
  const int c  = c0 + ci;
  const int h4 = tid & 255;
  const int h  = h4 * 4;
  const size_t base = ((size_t)(bb * 4096 + c * 64) * 1024 + h) * 2;
  const size_t ob   = (size_t)(bb * 4096 + c * 64) * 1024 + h;
  fv4 hc;
#pragma unroll
  for (int k = 0; k < 4; ++k) hc[k] = hcyL[ci][h4][k];
#pragma unroll 4
  for (int t = 0; t < 64; ++t) {
    hv8 v = *(const hv8*)(zh2 + base + (size_t)t * 2048);
    fv4 av = __builtin_convertvector(__builtin_shufflevector(v, v, 0, 2, 4, 6), fv4);
    fv4 bv = __builtin_convertvector(__builtin_shufflevector(v, v, 1, 3, 5, 7), fv4);
    hc = av * hc + bv;
    *(hv4*)(hout + ob + (size_t)t * 1024) = __builtin_convertvector(hc, hv4);
  }
}

// ---------------------------------------------------------------------------
extern "C" void kernel_launch(void* const* d_in, const int* in_sizes, int n_in,
                              void* d_out, int out_size, void* d_ws, size_t ws_size,
                              hipStream_t stream) {
  const float* x   = (const float*)d_in[0];
  const float* Wz0 = (const float*)d_in[1];
  const float* bz0 = (const float*)d_in[2];
  const float* Wh0 = (const float*)d_in[3];
  const float* bh0 = (const float*)d_in[4];
  const float* Wz1 = (const float*)d_in[5];
  const float* bz1 = (const float*)d_in[6];
  const float* Wh1 = (const float*)d_in[7];
  const float* bh1 = (const float*)d_in[8];
  const float* Wfc = (const float*)d_in[9];
  const float* bfc = (const float*)d_in[10];

  const int Mrows = 32768;  // B*T
  const int H = 1024, Din = 512, Dout = 512;

  // workspace layout (~205 MiB)
  char* w = (char*)d_ws;
  _Float16* zh2   = (_Float16*)w; w += (size_t)Mrows * 2 * H * 2;   // 128 MiB
  _Float16* hx    = (_Float16*)w; w += (size_t)Mrows * H * 2;       //  64 MiB
  _Float16* Wzh0t = (_Float16*)w; w += (size_t)2 * H * Din * 2;
  _Float16* Wzh1t = (_Float16*)w; w += (size_t)2 * H * H * 2;
  _Float16* Wft   = (_Float16*)w; w += (size_t)Dout * H * 2;
  float*    cA    = (float*)w;    w += (size_t)8 * 64 * H * 4;
  float*    cB    = (float*)w;    w += (size_t)8 * 64 * H * 4;
  _Float16* Xb    = hx;  // aliased: x(f16) dead before h0 is written

  // --- all preprocessing in ONE launch (transposes z=0..4, cvt z=5..8) ---
  prep_all<<<dim3(32, 32, 9), dim3(32, 8), 0, stream>>>(
      x, Wz0, Wh0, Wz1, Wh1, Wfc, Xb, Wzh0t, Wzh1t, Wft);

  // layer GEMM: 256x256 tiles -> 128 mtiles x 8 ntiles = 1024 blocks,
  // ntl2=3, 16 mtiles per XCD.
  // --- layer 0 ---
  gemm_gate<<<1024, 512, 0, stream>>>(Xb, Wzh0t, zh2, cA, cB, bz0, bh0, Din, 3, 16);
  scan_fused<<<256, 512, 0, stream>>>(cA, cB, zh2, hx);

  // --- layer 1 ---
  gemm_gate<<<1024, 512, 0, stream>>>(hx, Wzh1t, zh2, cA, cB, bz1, bh1, H, 3, 16);
  scan_fused<<<256, 512, 0, stream>>>(cA, cB, zh2, hx);

  // --- FC head: 128 mtiles x 2 ntiles = 256 blocks, ntl2=1 ---
  gemm_f16_bt<<<256, 512, 0, stream>>>(hx, Wft, (float*)d_out, bfc, Dout, H, 1, 16);
}

// Round 10
// 477.004 us; speedup vs baseline: 1.2019x; 1.2019x over previous
//
#include <hip/hip_runtime.h>

typedef __attribute__((ext_vector_type(4))) float fv4;
typedef __attribute__((ext_vector_type(8))) _Float16 hv8;
typedef __attribute__((ext_vector_type(4))) _Float16 hv4;
typedef __attribute__((ext_vector_type(2))) _Float16 hv2;

// ---------------------------------------------------------------------------
// async global->LDS 16B copy (wave-uniform LDS base + lane*16 semantics)
// ---------------------------------------------------------------------------
__device__ __forceinline__ void gload16(const void* g, void* l) {
  __builtin_amdgcn_global_load_lds(
      (const __attribute__((address_space(1))) unsigned int*)g,
      (__attribute__((address_space(3))) unsigned int*)l, 16, 0, 0);
}

// ---------------------------------------------------------------------------
// 256x256 tile GEMM core, 8 waves (2M x 4N), per-wave 128x64 output.
// R4/R8 structure -- measured optimum across 6 schedule brackets
// (155 us @ L1, MfmaUtil ~40%). Journal: phase-split (R2), 1-barrier (R3),
// full-prefetch (R6), 2-block TLP (R5), fat-wave (R7), scan-fusion (R9)
// all matched or regressed. Do not touch without a counter-backed theory.
// K in BK=32 steps through a 4-deep LDS ring (4 x 32 KiB = 128 KiB).
// Step: stage(s+3) -> vmcnt(8) -> s_barrier -> read b0(s), a47(s), a03(s+1)
// -> setprio(1) 32 MFMA setprio(0). vmcnt never 0 in main loop (tail 8->4->0).
// Swizzle (measured 0 conflicts): staged-side cg=(tid&3)^((tid>>3)&3) on the
// global source, fragment-side sq=quad^((r>>1)&3) on the ds_read.
// ---------------------------------------------------------------------------
struct GemmCore256 {
  const _Float16 *ap, *bp;   // per-thread pre-swizzled global sources
  size_t rstep;              // +128 rows in elements
  _Float16* ls;
  const _Float16 *fa, *fb;   // fragment read bases (ring slot 0)
  int wv;

  __device__ __forceinline__ void init(const _Float16* A, const _Float16* Bt,
                                       _Float16* lds, int m0, int n0, int K,
                                       int tid) {
    ls = lds;
    wv = tid >> 6;
    const int lane = tid & 63;
    const int wm = wv >> 2, wn = wv & 3;
    const int quad = lane >> 4, r = lane & 15;
    const int cg = (tid & 3) ^ ((tid >> 3) & 3);   // staged-side XOR swizzle
    ap = A  + (size_t)(m0 + (tid >> 2)) * K + cg * 8;
    bp = Bt + (size_t)(n0 + (tid >> 2)) * K + cg * 8;
    rstep = (size_t)128 * K;
    const int sq = quad ^ ((r >> 1) & 3);          // fragment-side swizzle
    fa = ls + (wm * 128 + r) * 32 + sq * 8;
    fb = ls + 8192 + (wn * 64 + r) * 32 + sq * 8;
  }

  __device__ __forceinline__ void stage4(int s) {   // full ring slot s&3
    _Float16* d = ls + (s & 3) * 16384 + wv * 512;
    const _Float16* a = ap + (size_t)s * 32;
    const _Float16* b = bp + (size_t)s * 32;
    gload16(a,         d);
    gload16(a + rstep, d + 4096);
    gload16(b,         d + 8192);
    gload16(b + rstep, d + 12288);
  }

  __device__ __forceinline__ void readA03(hv8 (&a)[4], int s) {
    const _Float16* fA = fa + (s & 3) * 16384;
#pragma unroll
    for (int t = 0; t < 4; ++t) a[t] = *(const hv8*)(fA + t * 512);
  }

  // one K-step; cur = prefetched a[0..3] of slot s; nxt filled for slot s+1
  template <int VM, bool STAGE>
  __device__ __forceinline__ void body(fv4 acc[8][4], hv8 (&nxt)[4],
                                       hv8 (&cur)[4], int s) {
    if (STAGE) stage4(s + 3);
    if constexpr (VM >= 0)
      asm volatile("s_waitcnt vmcnt(%0)" :: "n"(VM) : "memory");
    __builtin_amdgcn_s_barrier();
    asm volatile("" ::: "memory");   // pin LDS reads below the barrier
    const _Float16* fA = fa + (s & 3) * 16384;
    const _Float16* fB = fb + (s & 3) * 16384;
    hv8 b0[4], a47[4];
#pragma unroll
    for (int t = 0; t < 4; ++t) b0[t] = *(const hv8*)(fB + t * 512);
#pragma unroll
    for (int t = 0; t < 4; ++t) a47[t] = *(const hv8*)(fA + (t + 4) * 512);
    readA03(nxt, s + 1);             // prefetch: drains under the MFMAs
    __builtin_amdgcn_s_setprio(1);
#pragma unroll
    for (int tm = 0; tm < 4; ++tm)
#pragma unroll
      for (int tn = 0; tn < 4; ++tn)
        acc[tm][tn] = __builtin_amdgcn_mfma_f32_16x16x32_f16(cur[tm], b0[tn],
                                                             acc[tm][tn], 0, 0, 0);
#pragma unroll
    for (int tm = 0; tm < 4; ++tm)
#pragma unroll
      for (int tn = 0; tn < 4; ++tn)
        acc[tm + 4][tn] = __builtin_amdgcn_mfma_f32_16x16x32_f16(a47[tm], b0[tn],
                                                                 acc[tm + 4][tn], 0, 0, 0);
    __builtin_amdgcn_s_setprio(0);
  }

  __device__ __forceinline__ void bodyLast(fv4 acc[8][4], hv8 (&cur)[4], int s) {
    __builtin_amdgcn_s_barrier();
    asm volatile("" ::: "memory");
    const _Float16* fA = fa + (s & 3) * 16384;
    const _Float16* fB = fb + (s & 3) * 16384;
    hv8 b0[4], a47[4];
#pragma unroll
    for (int t = 0; t < 4; ++t) b0[t] = *(const hv8*)(fB + t * 512);
#pragma unroll
    for (int t = 0; t < 4; ++t) a47[t] = *(const hv8*)(fA + (t + 4) * 512);
    __builtin_amdgcn_s_setprio(1);
#pragma unroll
    for (int tm = 0; tm < 4; ++tm)
#pragma unroll
      for (int tn = 0; tn < 4; ++tn)
        acc[tm][tn] = __builtin_amdgcn_mfma_f32_16x16x32_f16(cur[tm], b0[tn],
                                                             acc[tm][tn], 0, 0, 0);
#pragma unroll
    for (int tm = 0; tm < 4; ++tm)
#pragma unroll
      for (int tn = 0; tn < 4; ++tn)
        acc[tm + 4][tn] = __builtin_amdgcn_mfma_f32_16x16x32_f16(a47[tm], b0[tn],
                                                                 acc[tm + 4][tn], 0, 0, 0);
    __builtin_amdgcn_s_setprio(0);
  }

  __device__ __forceinline__ void run(fv4 acc[8][4], int K) {
    const int ns = K >> 5;               // BK=32 steps (K = 512 or 1024, even)
    stage4(0); stage4(1); stage4(2);     // prime ring 3 deep (12 outstanding)
    asm volatile("s_waitcnt vmcnt(8)" ::: "memory");   // my slot-0 loads done
    __builtin_amdgcn_s_barrier();                       // collective
    asm volatile("" ::: "memory");
    hv8 p0[4], p1[4];                    // a[0..3] double-buffer (rule #20:
    readA03(p0, 0);                      //  static names, no runtime index)
    int s = 0;
    for (; s < ns - 4; s += 2) {
      body<8, true>(acc, p1, p0, s);
      body<8, true>(acc, p0, p1, s + 1);
    }
    body<8, true >(acc, p1, p0, ns - 4); // stages slot ns-1 (last)
    body<4, false>(acc, p0, p1, ns - 3); // tail guards: 8 -> 4 -> 0
    body<0, false>(acc, p1, p0, ns - 2);
    bodyLast(acc, p1, ns - 1);
  }
};

// XCD-colocation block swizzle (tile = 256): blocks sharing one A-strip get
// linear ids congruent mod 8 -> same XCD -> A-strip hits in its L2.
__device__ __forceinline__ void xcd_map(int bid, int ntl2, int mt_per_x,
                                        int& m0, int& n0) {
  const int xcd = bid & 7;
  const int k2  = bid >> 3;
  m0 = (xcd * mt_per_x + (k2 >> ntl2)) * 256;
  n0 = (k2 & ((1 << ntl2) - 1)) * 256;
}

// ---------------------------------------------------------------------------
// Fused layer GEMM + minGRU gate + scan phase A (256-tile, 8 waves).
// Btf[2048,K]: rows [b*64,b*64+32)=Wz cols, +32=Wh cols for j-block b.
// Per wave: 64-col slice -> tn 0,1 = zpre, tn 2,3 = hpre for j = jb+tn*16+r.
// Wave covers 128 rows = 2 scan chunks of 64 (tm 0-3 / tm 4-7); composition
// order identical to the verified version -> bit-identical cA/cB.
// ---------------------------------------------------------------------------
__global__ __launch_bounds__(512, 2)
void gemm_gate(const _Float16* __restrict__ A, const _Float16* __restrict__ Btf,
               _Float16* __restrict__ zh2,
               float* __restrict__ cA, float* __restrict__ cB,
               const float* __restrict__ bz, const float* __restrict__ bh,
               int K, int ntl2, int mt_per_x) {
  __shared__ _Float16 lds[4 * 16384];   // 128 KiB ring
  const int tid  = threadIdx.x;
  const int lane = tid & 63;
  const int wave = tid >> 6;
  const int wm = wave >> 2, wn = wave & 3;
  const int quad = lane >> 4, r = lane & 15;
  int m0, n0;
  xcd_map(blockIdx.x, ntl2, mt_per_x, m0, n0);

  GemmCore256 core;
  core.init(A, Btf, lds, m0, n0, K, tid);
  fv4 acc[8][4] = {};
  core.run(acc, K);

  // C/D layout: col = lane&15, row = quad*4 + reg (m89-verified).
  const int jb   = (n0 + wn * 64) >> 1;
  const int row0 = m0 + wm * 128 + quad * 4;
  const int cb   = (m0 >> 6) + wm * 2;   // first chunk index of this wave
#pragma unroll
  for (int tn = 0; tn < 2; ++tn) {
    const int j = jb + tn * 16 + r;
    const float bzv = bz[j];
    const float bhv = bh[j];
#pragma unroll
    for (int tg = 0; tg < 2; ++tg) {     // 64-row chunk within the wave
      float qA[4], qB[4];
#pragma unroll
      for (int tq = 0; tq < 4; ++tq) {
        const int tm = tg * 4 + tq;
        float sA = 1.0f, sB = 0.0f;
#pragma unroll
        for (int r2 = 0; r2 < 4; ++r2) {
          const float zpre = acc[tm][tn][r2] + bzv;
          const float hpre = acc[tm][tn + 2][r2] + bhv;
          const float z = 1.0f / (1.0f + __expf(-zpre));
          const _Float16 a16 = (_Float16)(1.0f - z);
          const _Float16 b16 = (_Float16)(z * hpre);
          hv2 ab = {a16, b16};
          *(hv2*)(zh2 + ((size_t)(row0 + tm * 16 + r2) * 1024 + j) * 2) = ab;
          const float af = (float)a16, bf = (float)b16;
          sB = af * sB + bf;   // ordered fold, r2 ascending
          sA = sA * af;
        }
        qA[tq] = sA; qB[tq] = sB;
      }
      // inclusive scan across quads (rows 16tq+4q+r2; quad ascending)
#pragma unroll
      for (int tq = 0; tq < 4; ++tq) {
        float Av = qA[tq], Bv = qB[tq];
        float Ap = __shfl_up(Av, 16, 64);
        float Bp = __shfl_up(Bv, 16, 64);
        if (quad >= 1) { Bv = Av * Bp + Bv; Av = Ap * Av; }
        Ap = __shfl_up(Av, 32, 64);
        Bp = __shfl_up(Bv, 32, 64);
        if (quad >= 2) { Bv = Av * Bp + Bv; Av = Ap * Av; }
        qA[tq] = Av; qB[tq] = Bv;
      }
      if (quad == 3) {   // lane holds full 16-row composition per tq
        float CA = 1.0f, CB = 0.0f;
#pragma unroll
        for (int tq = 0; tq < 4; ++tq) { CB = qA[tq] * CB + qB[tq]; CA *= qA[tq]; }
        cA[(size_t)(cb + tg) * 1024 + j] = CA;
        cB[(size_t)(cb + tg) * 1024 + j] = CB;
      }
    }
  }
}

// ---------------------------------------------------------------------------
// Plain GEMM (FC head): C[M,N] fp32 = A[M,K] f16 @ Bt[N,K]^T + bias
// ---------------------------------------------------------------------------
__global__ __launch_bounds__(512, 2)
void gemm_f16_bt(const _Float16* __restrict__ A, const _Float16* __restrict__ Bt,
                 float* __restrict__ C, const float* __restrict__ bias,
                 int N, int K, int ntl2, int mt_per_x) {
  __shared__ _Float16 lds[4 * 16384];
  const int tid  = threadIdx.x;
  const int lane = tid & 63;
  const int wave = tid >> 6;
  const int wm = wave >> 2, wn = wave & 3;
  const int quad = lane >> 4, r = lane & 15;
  int m0, n0;
  xcd_map(blockIdx.x, ntl2, mt_per_x, m0, n0);

  GemmCore256 core;
  core.init(A, Bt, lds, m0, n0, K, tid);
  fv4 acc[8][4] = {};
  core.run(acc, K);

  const int col0 = n0 + wn * 64 + r;
  const int row0 = m0 + wm * 128 + quad * 4;
#pragma unroll
  for (int tn = 0; tn < 4; ++tn) {
    const int col = col0 + tn * 16;
    const float bs = bias[col];
#pragma unroll
    for (int tm = 0; tm < 8; ++tm) {
#pragma unroll
      for (int r2 = 0; r2 < 4; ++r2) {
        C[(size_t)(row0 + tm * 16 + r2) * N + col] = acc[tm][tn][r2] + bs;
      }
    }
  }
}

// ---------------------------------------------------------------------------
// elementwise fp32 -> f16
// ---------------------------------------------------------------------------
__global__ void cvt_f16(const float* __restrict__ x, _Float16* __restrict__ y) {
  size_t i = ((size_t)blockIdx.x * 256 + threadIdx.x) * 4;
  fv4 v = *(const fv4*)(x + i);
  *(hv4*)(y + i) = __builtin_convertvector(v, hv4);
}

// ---------------------------------------------------------------------------
// ALL weight transposes in ONE launch (saves 4 small-kernel launch latencies).
// z selects the job; ragged shapes early-exit. Per-z body identical to the
// verified transpose_cvt: W[K,N] f32 -> Wt f16, cols j = bx*32+i -> rows
// bx*mult + off + i.
// ---------------------------------------------------------------------------
__global__ void transpose_cvt_all(const float* __restrict__ Wz0,
                                  const float* __restrict__ Wh0,
                                  const float* __restrict__ Wz1,
                                  const float* __restrict__ Wh1,
                                  const float* __restrict__ Wfc,
                                  _Float16* __restrict__ Wzh0t,
                                  _Float16* __restrict__ Wzh1t,
                                  _Float16* __restrict__ Wft) {
  const int z = blockIdx.z;
  const float* W; _Float16* Wt; int K, N, mult, off;
  if (z == 0)      { W = Wz0; Wt = Wzh0t; K = 512;  N = 1024; mult = 64; off = 0;  }
  else if (z == 1) { W = Wh0; Wt = Wzh0t; K = 512;  N = 1024; mult = 64; off = 32; }
  else if (z == 2) { W = Wz1; Wt = Wzh1t; K = 1024; N = 1024; mult = 64; off = 0;  }
  else if (z == 3) { W = Wh1; Wt = Wzh1t; K = 1024; N = 1024; mult = 64; off = 32; }
  else             { W = Wfc; Wt = Wft;   K = 1024; N = 512;  mult = 32; off = 0;  }
  if (blockIdx.x * 32 >= (unsigned)N || blockIdx.y * 32 >= (unsigned)K) return;

  __shared__ float tile[32][33];
  const int tx = threadIdx.x, ty = threadIdx.y;
  const int n  = blockIdx.x * 32 + tx;
  const int kb = blockIdx.y * 32;
  for (int i = ty; i < 32; i += 8)
    tile[i][tx] = W[(size_t)(kb + i) * N + n];
  __syncthreads();
  const int k = kb + tx;
  for (int i = ty; i < 32; i += 8)
    Wt[(size_t)(blockIdx.x * mult + off + i) * K + k] = (_Float16)tile[tx][i];
}

// ---------------------------------------------------------------------------
// phase B: wave-parallel Hillis-Steele over the 64 chunks (lane = chunk).
// hcy[c] = h entering chunk c (exclusive scan, h0 = 0).
// ---------------------------------------------------------------------------
__global__ void scan_phaseB(const float* __restrict__ cA, const float* __restrict__ cB,
                            float* __restrict__ hcy) {
  const int gtid = blockIdx.x * 256 + threadIdx.x;  // 2048 waves * 64
  const int lane = gtid & 63;
  const int wid  = gtid >> 6;
  const int h  = (wid & 255) * 4;
  const int bb = wid >> 8;
  const size_t o = (size_t)(bb * 64 + lane) * 1024 + h;
  fv4 Aa = *(const fv4*)(cA + o);
  fv4 Bv = *(const fv4*)(cB + o);
#pragma unroll
  for (int d = 1; d < 64; d <<= 1) {
    fv4 Ap, Bp;
#pragma unroll
    for (int k = 0; k < 4; ++k) {
      Ap[k] = __shfl_up(Aa[k], d, 64);
      Bp[k] = __shfl_up(Bv[k], d, 64);
    }
    if (lane >= d) {
      Bv = Aa * Bp + Bv;
      Aa = Ap * Aa;
    }
  }
  fv4 hc;
#pragma unroll
  for (int k = 0; k < 4; ++k) hc[k] = __shfl_up(Bv[k], 1, 64);
  if (lane == 0) { hc.x = 0.f; hc.y = 0.f; hc.z = 0.f; hc.w = 0.f; }
  *(fv4*)(hcy + o) = hc;
}

// phase C: replay chunk with correct carry, emit h (f16, [M,1024])
__global__ void scan_phaseC(const _Float16* __restrict__ zh2,
                            const float* __restrict__ hcy,
                            _Float16* __restrict__ hout) {
  const int idx = blockIdx.x * 256 + threadIdx.x;
  const int h  = (idx & 255) * 4;
  const int c  = (idx >> 8) & 63;
  const int bb = idx >> 14;
  const size_t base = ((size_t)(bb * 4096 + c * 64) * 1024 + h) * 2;
  const size_t ob   = (size_t)(bb * 4096 + c * 64) * 1024 + h;
  const size_t o    = (size_t)(bb * 64 + c) * 1024 + h;
  fv4 hc = *(const fv4*)(hcy + o);
#pragma unroll 4
  for (int t = 0; t < 64; ++t) {
    hv8 v = *(const hv8*)(zh2 + base + (size_t)t * 2048);
    fv4 av = __builtin_convertvector(__builtin_shufflevector(v, v, 0, 2, 4, 6), fv4);
    fv4 bv = __builtin_convertvector(__builtin_shufflevector(v, v, 1, 3, 5, 7), fv4);
    hc = av * hc + bv;
    *(hv4*)(hout + ob + (size_t)t * 1024) = __builtin_convertvector(hc, hv4);
  }
}

// ---------------------------------------------------------------------------
extern "C" void kernel_launch(void* const* d_in, const int* in_sizes, int n_in,
                              void* d_out, int out_size, void* d_ws, size_t ws_size,
                              hipStream_t stream) {
  const float* x   = (const float*)d_in[0];
  const float* Wz0 = (const float*)d_in[1];
  const float* bz0 = (const float*)d_in[2];
  const float* Wh0 = (const float*)d_in[3];
  const float* bh0 = (const float*)d_in[4];
  const float* Wz1 = (const float*)d_in[5];
  const float* bz1 = (const float*)d_in[6];
  const float* Wh1 = (const float*)d_in[7];
  const float* bh1 = (const float*)d_in[8];
  const float* Wfc = (const float*)d_in[9];
  const float* bfc = (const float*)d_in[10];

  const int Mrows = 32768;  // B*T
  const int H = 1024, Din = 512, Dout = 512;

  // workspace layout (~205 MiB)
  char* w = (char*)d_ws;
  _Float16* zh2   = (_Float16*)w; w += (size_t)Mrows * 2 * H * 2;   // 128 MiB
  _Float16* hx    = (_Float16*)w; w += (size_t)Mrows * H * 2;       //  64 MiB
  _Float16* Wzh0t = (_Float16*)w; w += (size_t)2 * H * Din * 2;
  _Float16* Wzh1t = (_Float16*)w; w += (size_t)2 * H * H * 2;
  _Float16* Wft   = (_Float16*)w; w += (size_t)Dout * H * 2;
  float*    cA    = (float*)w;    w += (size_t)8 * 64 * H * 4;
  float*    cB    = (float*)w;    w += (size_t)8 * 64 * H * 4;
  float*    hcy   = (float*)w;    w += (size_t)8 * 64 * H * 4;
  _Float16* Xb    = hx;  // aliased: x(f16) dead before h0 is written

  // --- input conversions (fused z|h row mapping; transposes in ONE launch) ---
  cvt_f16<<<Mrows * Din / 1024, 256, 0, stream>>>(x, Xb);
  transpose_cvt_all<<<dim3(32, 32, 5), dim3(32, 8), 0, stream>>>(
      Wz0, Wh0, Wz1, Wh1, Wfc, Wzh0t, Wzh1t, Wft);

  // layer GEMM: 256x256 tiles -> 128 mtiles x 8 ntiles = 1024 blocks,
  // ntl2=3, 16 mtiles per XCD.
  // --- layer 0 ---
  gemm_gate<<<1024, 512, 0, stream>>>(Xb, Wzh0t, zh2, cA, cB, bz0, bh0, Din, 3, 16);
  scan_phaseB<<<512, 256, 0, stream>>>(cA, cB, hcy);
  scan_phaseC<<<512, 256, 0, stream>>>(zh2, hcy, hx);

  // --- layer 1 ---
  gemm_gate<<<1024, 512, 0, stream>>>(hx, Wzh1t, zh2, cA, cB, bz1, bh1, H, 3, 16);
  scan_phaseB<<<512, 256, 0, stream>>>(cA, cB, hcy);
  scan_phaseC<<<512, 256, 0, stream>>>(zh2, hcy, hx);

  // --- FC head: 128 mtiles x 2 ntiles = 256 blocks, ntl2=1 ---
  gemm_f16_bt<<<256, 512, 0, stream>>>(hx, Wft, (float*)d_out, bfc, Dout, H, 1, 16);
}